// Round 1
// baseline (372.256 us; speedup 1.0000x reference)
//
#include <hip/hip_runtime.h>
#include <hip/hip_bf16.h>

typedef __bf16 bf16_t;
typedef __bf16 bf16x2 __attribute__((ext_vector_type(2)));
typedef __bf16 bf16x4v __attribute__((ext_vector_type(4)));
typedef __bf16 bf16x8 __attribute__((ext_vector_type(8)));
typedef float f32x4 __attribute__((ext_vector_type(4)));

#define LOG2E 1.4426950408889634f

// ---------------- fp32 -> bf16 conversion ----------------
__global__ __launch_bounds__(256) void cvt_f32_bf16(const float* __restrict__ in,
                                                    bf16_t* __restrict__ out, int n4) {
  int i = blockIdx.x * 256 + threadIdx.x;
  if (i < n4) {
    float4 v = ((const float4*)in)[i];
    bf16x4v o;
    o[0] = (__bf16)v.x; o[1] = (__bf16)v.y; o[2] = (__bf16)v.z; o[3] = (__bf16)v.w;
    *(bf16x4v*)(out + (size_t)i * 4) = o;
  }
}

// ---------------- RoPE cos/sin tables: [S=2048][64] ----------------
__global__ __launch_bounds__(256) void rope_tables(float* __restrict__ cosT,
                                                   float* __restrict__ sinT) {
  int idx = blockIdx.x * 256 + threadIdx.x;   // 2048*64 = 131072
  int s = idx >> 6, i = idx & 63;
  // inv = 1e6^(-i/64) = 2^(-i/64 * log2(1e6))
  float inv = __builtin_amdgcn_exp2f(-(float)i * (19.931568569324174f / 64.0f));
  float f = (float)s * inv;
  cosT[idx] = cosf(f);
  sinT[idx] = sinf(f);
}

// ---------------- bf16 NT GEMM: C[m,n] = sum_k A[m,k]*B[n,k], fp32 out ----------
// 128x128 tile, BK=64, 256 threads (4 waves, 2x2), 16x16x32 MFMA  (m97 structure)
__global__ __launch_bounds__(256) void gemm_nt(const bf16_t* __restrict__ A,
                                               const bf16_t* __restrict__ B,
                                               float* __restrict__ C,
                                               int M, int N, int K) {
  __shared__ bf16_t As[128 * 64];
  __shared__ bf16_t Bs[128 * 64];
  int nb = N >> 7;
  int bm = blockIdx.x / nb, bn = blockIdx.x % nb;
  int m0 = bm << 7, n0 = bn << 7;
  int tid = threadIdx.x, lane = tid & 63, wv = tid >> 6;
  int wr = wv >> 1, wc = wv & 1, lr = lane & 15, g = lane >> 4;

  f32x4 acc[4][4];
#pragma unroll
  for (int i = 0; i < 4; i++)
#pragma unroll
    for (int j = 0; j < 4; j++)
#pragma unroll
      for (int r = 0; r < 4; r++) acc[i][j][r] = 0.f;

  int srow = wv * 32 + (lane >> 3);
  int scol = (lane & 7) * 8;
  const bf16_t* aBase = A + (size_t)(m0 + srow) * K + scol;
  const bf16_t* bBase = B + (size_t)(n0 + srow) * K + scol;

  for (int k0 = 0; k0 < K; k0 += 64) {
#pragma unroll
    for (int i = 0; i < 4; i++) {
      __builtin_amdgcn_global_load_lds(
          (const __attribute__((address_space(1))) void*)(aBase + (size_t)i * 8 * K + k0),
          (__attribute__((address_space(3))) void*)&As[(wv * 32 + i * 8) * 64], 16, 0, 0);
      __builtin_amdgcn_global_load_lds(
          (const __attribute__((address_space(1))) void*)(bBase + (size_t)i * 8 * K + k0),
          (__attribute__((address_space(3))) void*)&Bs[(wv * 32 + i * 8) * 64], 16, 0, 0);
    }
    __syncthreads();
#pragma unroll
    for (int ks = 0; ks < 2; ks++) {
      bf16x8 af[4], bfv[4];
#pragma unroll
      for (int mi = 0; mi < 4; mi++)
        af[mi] = *(const bf16x8*)&As[(wr * 64 + mi * 16 + lr) * 64 + ks * 32 + g * 8];
#pragma unroll
      for (int ni = 0; ni < 4; ni++)
        bfv[ni] = *(const bf16x8*)&Bs[(wc * 64 + ni * 16 + lr) * 64 + ks * 32 + g * 8];
#pragma unroll
      for (int mi = 0; mi < 4; mi++)
#pragma unroll
        for (int ni = 0; ni < 4; ni++)
          acc[mi][ni] = __builtin_amdgcn_mfma_f32_16x16x32_bf16(af[mi], bfv[ni], acc[mi][ni], 0, 0, 0);
    }
    __syncthreads();
  }

#pragma unroll
  for (int mi = 0; mi < 4; mi++)
#pragma unroll
    for (int ni = 0; ni < 4; ni++) {
      int m = m0 + wr * 64 + mi * 16 + g * 4;
      int n = n0 + wc * 64 + ni * 16 + lr;
#pragma unroll
      for (int r = 0; r < 4; r++) C[(size_t)(m + r) * N + n] = acc[mi][ni][r];
    }
}

// ---------------- fused per-head LayerNorm + RoPE -> bf16 Q(B,H,S,D), K(B,KV,S,D) ----
__global__ __launch_bounds__(256) void ln_rope(const float* __restrict__ qkv,
                                               const float* __restrict__ qw, const float* __restrict__ qb,
                                               const float* __restrict__ kw, const float* __restrict__ kb,
                                               const float* __restrict__ cosT, const float* __restrict__ sinT,
                                               bf16_t* __restrict__ Qr, bf16_t* __restrict__ Kr) {
  int row = blockIdx.x;              // b*2048 + s
  int b = row >> 11, s = row & 2047;
  int lane = threadIdx.x & 63, wv = threadIdx.x >> 6;
  float c = cosT[(s << 6) + lane], sn = sinT[(s << 6) + lane];
  const float* base = qkv + (size_t)row * 5120;
#pragma unroll
  for (int i = 0; i < 5; i++) {
    int head = wv * 5 + i;           // 0..15 = q heads, 16..19 = k heads
    bool isq = head < 16;
    int off = isq ? (head << 7) : (4096 + ((head - 16) << 7));
    float2 x = *(const float2*)(base + off + (lane << 1));
    float sum = x.x + x.y;
#pragma unroll
    for (int m = 1; m < 64; m <<= 1) sum += __shfl_xor(sum, m);
    float mu = sum * 0.0078125f;
    float x0 = x.x - mu, x1 = x.y - mu;
    float vs = x0 * x0 + x1 * x1;
#pragma unroll
    for (int m = 1; m < 64; m <<= 1) vs += __shfl_xor(vs, m);
    float rs = rsqrtf(vs * 0.0078125f + 1e-6f);
    const float* w = isq ? qw : kw;
    const float* bb = isq ? qb : kb;
    float y0 = x0 * rs * w[lane << 1] + bb[lane << 1];
    float y1 = x1 * rs * w[(lane << 1) + 1] + bb[(lane << 1) + 1];
    float o0 = y0 * c - y1 * sn;
    float o1 = y0 * sn + y1 * c;
    bf16x2 ov; ov[0] = (__bf16)o0; ov[1] = (__bf16)o1;
    size_t dst = isq ? ((((size_t)(b * 16 + head)) * 2048 + s) * 128 + (lane << 1))
                     : ((((size_t)(b * 4 + (head - 16))) * 2048 + s) * 128 + (lane << 1));
    *(bf16x2*)((isq ? Qr : Kr) + dst) = ov;
  }
}

// ---------------- V transpose: qkv v-slice (B,S,KV,D) -> Vt (B,KV,D,S) bf16 -------
__global__ __launch_bounds__(256) void vtrans(const float* __restrict__ qkv,
                                              bf16_t* __restrict__ Vt) {
  int bid = blockIdx.x;              // ((b*4+kv)*64 + sb)
  int sb = bid & 63, kv = (bid >> 6) & 3, b = bid >> 8;
  int s0 = sb << 5;
  __shared__ bf16_t T[128 * 33];
  int tid = threadIdx.x;
#pragma unroll
  for (int i = 0; i < 16; i++) {
    int idx = i * 256 + tid;         // 0..4095
    int r = idx >> 7, d = idx & 127;
    float v = qkv[((size_t)(b * 2048 + s0 + r)) * 5120 + 4608 + (kv << 7) + d];
    T[d * 33 + r] = (__bf16)v;
  }
  __syncthreads();
#pragma unroll
  for (int j = 0; j < 16; j++) {
    int idx = j * 256 + tid;
    int d = idx >> 5, sc = idx & 31;
    Vt[(((size_t)(b * 4 + kv)) * 128 + d) * 2048 + s0 + sc] = T[d * 33 + sc];
  }
}

// ---------------- causal GQA flash attention + sigmoid gate -> ag bf16 (B,S,H*D) ----
__device__ __forceinline__ int fsw(int r) { return (r & 3) | ((r & 8) >> 1); }

__global__ __launch_bounds__(256) void attn(const bf16_t* __restrict__ Qr,
                                            const bf16_t* __restrict__ Kr,
                                            const bf16_t* __restrict__ Vt,
                                            const float* __restrict__ qkv,
                                            bf16_t* __restrict__ ag) {
  __shared__ bf16_t Ks[64 * 128];    // K tile, chunk-XOR swizzled
  __shared__ bf16_t Vs[128 * 72];    // V^T tile, +8 pad
  int bid = blockIdx.x;
  int qb = bid & 31, h = (bid >> 5) & 15, b = bid >> 9;
  int kvh = h >> 2;
  int tid = threadIdx.x, lane = tid & 63, wv = tid >> 6;
  int lr = lane & 15, g = lane >> 4;
  int q0w = (qb << 6) + (wv << 4);
  int qrow = q0w + lr;

  const bf16_t* Qg = Qr + (((size_t)(b * 16 + h)) * 2048 + qrow) * 128;
  bf16x8 qf[4];
#pragma unroll
  for (int ds = 0; ds < 4; ds++) qf[ds] = *(const bf16x8*)(Qg + ds * 32 + g * 8);

  const bf16_t* Kg = Kr + ((size_t)(b * 4 + kvh)) * 2048 * 128;
  const bf16_t* Vg = Vt + ((size_t)(b * 4 + kvh)) * 128 * 2048;

  f32x4 oacc[8];
#pragma unroll
  for (int i = 0; i < 8; i++)
#pragma unroll
    for (int r = 0; r < 4; r++) oacc[i][r] = 0.f;
  float mrun = -1e30f, lsum = 0.f;

  int kvend = (qb + 1) << 6;
  const float K2 = 0.08838834764831843f * LOG2E;   // (1/sqrt(128)) * log2(e)
  int r0base = ((lr >> 2) << 3) + (lr & 3);        // pi(lr)

  for (int kv0 = 0; kv0 < kvend; kv0 += 64) {
    // stage K (64x128, swizzled) and V^T (128x64, padded) via regs
#pragma unroll
    for (int pp = 0; pp < 4; pp++) {
      int idx = pp * 256 + tid;
      int r = idx >> 4, ck = idx & 15;
      bf16x8 kvv = *(const bf16x8*)(Kg + (size_t)(kv0 + r) * 128 + ck * 8);
      *(bf16x8*)&Ks[r * 128 + ((ck ^ fsw(r)) << 3)] = kvv;
      int d = idx >> 3, cv = idx & 7;
      bf16x8 vv = *(const bf16x8*)(Vg + (size_t)d * 2048 + kv0 + cv * 8);
      *(bf16x8*)&Vs[d * 72 + (cv << 3)] = vv;
    }
    __syncthreads();
#pragma unroll
    for (int ss = 0; ss < 2; ss++) {
      int kvb = ss << 5;
      int r0 = kvb + r0base, r1 = r0 + 4;
      f32x4 st0, st1;
#pragma unroll
      for (int r = 0; r < 4; r++) { st0[r] = 0.f; st1[r] = 0.f; }
#pragma unroll
      for (int ds = 0; ds < 4; ds++) {
        bf16x8 a0 = *(const bf16x8*)&Ks[r0 * 128 + (((ds * 4 + g) ^ fsw(r0)) << 3)];
        bf16x8 a1 = *(const bf16x8*)&Ks[r1 * 128 + (((ds * 4 + g) ^ fsw(r1)) << 3)];
        st0 = __builtin_amdgcn_mfma_f32_16x16x32_bf16(a0, qf[ds], st0, 0, 0, 0);
        st1 = __builtin_amdgcn_mfma_f32_16x16x32_bf16(a1, qf[ds], st1, 0, 0, 0);
      }
      int kvabs = kv0 + kvb + (g << 3);
      float t[8];
#pragma unroll
      for (int r = 0; r < 4; r++) {
        t[r]     = (kvabs + r     <= qrow) ? st0[r] * K2 : -1e30f;
        t[4 + r] = (kvabs + 4 + r <= qrow) ? st1[r] * K2 : -1e30f;
      }
      float pm = t[0];
#pragma unroll
      for (int i = 1; i < 8; i++) pm = fmaxf(pm, t[i]);
      pm = fmaxf(pm, __shfl_xor(pm, 16));
      pm = fmaxf(pm, __shfl_xor(pm, 32));
      float mnew = fmaxf(mrun, pm);
      float corr = __builtin_amdgcn_exp2f(mrun - mnew);
      float p[8], ps = 0.f;
#pragma unroll
      for (int i = 0; i < 8; i++) { p[i] = __builtin_amdgcn_exp2f(t[i] - mnew); ps += p[i]; }
      ps += __shfl_xor(ps, 16);
      ps += __shfl_xor(ps, 32);
      lsum = lsum * corr + ps;
      mrun = mnew;
      bf16x8 pb;
#pragma unroll
      for (int i = 0; i < 8; i++) pb[i] = (__bf16)p[i];
#pragma unroll
      for (int dt = 0; dt < 8; dt++) {
#pragma unroll
        for (int r = 0; r < 4; r++) oacc[dt][r] *= corr;
        bf16x8 va = *(const bf16x8*)&Vs[(dt * 16 + lr) * 72 + kvb + (g << 3)];
        oacc[dt] = __builtin_amdgcn_mfma_f32_16x16x32_bf16(va, pb, oacc[dt], 0, 0, 0);
      }
    }
    __syncthreads();
  }

  float invl = 1.0f / lsum;
  size_t obase = ((size_t)b * 2048 + qrow) * 2048 + (h << 7);
  size_t gbase = ((size_t)b * 2048 + qrow) * 5120 + 2048 + (h << 7);
#pragma unroll
  for (int dt = 0; dt < 8; dt++) {
#pragma unroll
    for (int r = 0; r < 4; r++) {
      int d = dt * 16 + (g << 2) + r;
      float gt = qkv[gbase + d];
      float sg = 1.0f / (1.0f + __builtin_amdgcn_exp2f(-gt * LOG2E));
      ag[obase + d] = (__bf16)(oacc[dt][r] * invl * sg);
    }
  }
}

// ---------------- launch ----------------
extern "C" void kernel_launch(void* const* d_in, const int* in_sizes, int n_in,
                              void* d_out, int out_size, void* d_ws, size_t ws_size,
                              hipStream_t stream) {
  const float* x    = (const float*)d_in[0];
  const float* wqkv = (const float*)d_in[1];
  const float* wo   = (const float*)d_in[2];
  const float* qnw  = (const float*)d_in[3];
  const float* qnb  = (const float*)d_in[4];
  const float* knw  = (const float*)d_in[5];
  const float* knb  = (const float*)d_in[6];
  float* out = (float*)d_out;

  char* p = (char*)d_ws;
  bf16_t* xb  = (bf16_t*)p;           // 16 MB, reused as ag after GEMM1
  bf16_t* ag  = xb;
  p += (size_t)16777216;
  bf16_t* wqb = (bf16_t*)p;           // 20 MB, reused as Qr after GEMM1
  bf16_t* Qr  = wqb;
  p += (size_t)20971520;
  bf16_t* wob = (bf16_t*)p; p += (size_t)8388608;
  float*  qkv = (float*)p;  p += (size_t)83886080;
  bf16_t* Kr  = (bf16_t*)p; p += (size_t)4194304;
  bf16_t* Vt  = (bf16_t*)p; p += (size_t)4194304;
  float* cosT = (float*)p;  p += (size_t)524288;
  float* sinT = (float*)p;  p += (size_t)524288;

  cvt_f32_bf16<<<8192, 256, 0, stream>>>(x, xb, 2097152);
  cvt_f32_bf16<<<10240, 256, 0, stream>>>(wqkv, wqb, 2621440);
  cvt_f32_bf16<<<4096, 256, 0, stream>>>(wo, wob, 1048576);
  rope_tables<<<512, 256, 0, stream>>>(cosT, sinT);

  // qkv = x @ w_qkv^T   (4096 x 5120 x K=2048)
  gemm_nt<<<1280, 256, 0, stream>>>(xb, wqb, qkv, 4096, 5120, 2048);

  ln_rope<<<4096, 256, 0, stream>>>(qkv, qnw, qnb, knw, knb, cosT, sinT, Qr, Kr);
  vtrans<<<512, 256, 0, stream>>>(qkv, Vt);

  attn<<<1024, 256, 0, stream>>>(Qr, Kr, Vt, qkv, ag);

  // out = ag @ w_o^T    (4096 x 2048 x K=2048)
  gemm_nt<<<512, 256, 0, stream>>>(ag, wob, out, 4096, 2048, 2048);
}